// Round 11
// baseline (132.188 us; speedup 1.0000x reference)
//
#include <hip/hip_runtime.h>

#define BB 16      // batch
#define SS 48      // seq len
#define VV 16000   // vocab
#define DD 128     // embed
#define NC (DD / 4)            // 32 float4 per row
#define TVR 64                 // v-rows per tile (16 KB bf16 in LDS)
#define NTH 256                // 4 waves; wave wv owns rows wv*16..wv*16+15
#define TPB 10                 // tiles per block
#define BPS (VV / TVR / TPB)   // 25 blocks per s (25*10*64 = 16000 exactly)
#define F4T (TVR * NC)         // 2048 float4 per tile

constexpr float EPS   = 1e-8f;
constexpr float SCALE = 10.0f;

typedef __attribute__((ext_vector_type(8))) short bf16x8;
typedef __attribute__((ext_vector_type(4))) float f32x4;

__device__ __forceinline__ unsigned short f2bf_rne(float x) {
    union { float f; unsigned u; } v; v.f = x;
    unsigned r = v.u + 0x7fffu + ((v.u >> 16) & 1u);   // round-to-nearest-even
    return (unsigned short)(r >> 16);
}
__device__ __forceinline__ float bf2f(unsigned short h) {
    union { unsigned u; float f; } t; t.u = ((unsigned)h) << 16; return t.f;
}

// Kernel 1 (verified R2-R10): per-batch causal prefix context, f32-normalized,
// emitted as bf16 ctx_bf[S][B][D]. One block = one batch, 64 threads.
__global__ __launch_bounds__(64) void ctx_kernel(
    const int*      __restrict__ tokens,   // [B,S]
    const float*    __restrict__ scalars,  // [S,V]
    const float*    __restrict__ wvecs,    // [S,V,D]
    unsigned short* __restrict__ ctx_bf)   // [S,B,D] bf16
{
    const int b    = blockIdx.x;
    const int lane = threadIdx.x;  // 0..63

    float a[SS], w0[SS], w1[SS];
    #pragma unroll
    for (int s = 0; s < SS; ++s) {
        const int tok = tokens[b * SS + s];
        a[s] = scalars[(size_t)s * VV + tok];
        const float* wp = wvecs + ((size_t)s * VV + tok) * DD;
        w0[s] = wp[lane];
        w1[s] = wp[lane + 64];
    }

    float run0 = 0.f, run1 = 0.f;
    #pragma unroll
    for (int s = 0; s < SS; ++s) {
        float p = fmaf(run0, run0, run1 * run1);
        #pragma unroll
        for (int off = 32; off > 0; off >>= 1)
            p += __shfl_xor(p, off);
        const float denom = fmaxf(sqrtf(p), EPS);  // torch F.normalize semantics
        unsigned short* o = ctx_bf + ((size_t)s * BB + b) * DD;
        o[lane]      = f2bf_rne(run0 / denom);
        o[lane + 64] = f2bf_rne(run1 / denom);
        run0 = fmaf(a[s], w0[s], run0);   // position s contributes to positions > s
        run1 = fmaf(a[s], w1[s], run1);
    }
}

// Kernel 2: out[b,s,v] = SCALE * dot(ctx_n, emb[s,v,:]) / max(||emb[s,v,:]||,eps)
// via mfma_f32_16x16x32_bf16. Multi-tile reg-staged pipeline: per tile,
// convert staged regs into swizzled LDS, ISSUE next tile's 8 dwordx4 (stay in
// flight across the whole compute phase), raw s_barrier + lgkmcnt(0) only
// (loads are private registers -> legal to cross), per-wave norms via
// shfl_xor(16|32), 4 MFMAs, scaled coalesced store.
__global__ __launch_bounds__(NTH) void logits_kernel(
    const unsigned short* __restrict__ ctx_bf,  // [S,B,D] bf16
    const float*          __restrict__ emb,     // [S,V,D] f32
    float*                __restrict__ out)     // [B,S,V] f32
{
    const int s    = blockIdx.y;
    const int t0   = blockIdx.x * TPB;   // first tile of this block
    const int tid  = threadIdx.x;        // 0..255
    const int lane = tid & 63;
    const int wv   = tid >> 6;           // wave 0..3

    __shared__ unsigned short eL[TVR * DD];  // 16 KB bf16 tile, swizzled 16B slots

    // A-fragments: ctx bf16 (4 KB per s, L2-resident). A-row(batch)=lane&15,
    // k=(lane>>4)*8 + sl*32 + 0..7. Loaded once per block. (R10-verified.)
    bf16x8 afrag[4];
    {
        const unsigned short* cb = ctx_bf + ((size_t)s * BB + (lane & 15)) * DD
                                 + (lane >> 4) * 8;
        #pragma unroll
        for (int sl = 0; sl < 4; ++sl)
            afrag[sl] = *(const bf16x8*)(cb + sl * 32);
    }

    const float4* ebase = (const float4*)emb + (size_t)s * VV * NC;

    // Prologue: stage tile t0 into registers (8 x dwordx4, 1 KB/wave-inst).
    float4 g[8];
    #pragma unroll
    for (int i = 0; i < 8; ++i)
        g[i] = ebase[(size_t)t0 * F4T + tid + i * NTH];

    const int slot4 = tid & 31;        // float4-slot within row
    const int s16   = slot4 >> 1;      // 16B slot (8 bf16)
    const int hw    = slot4 & 1;       // half within 16B slot
    const int r     = wv * 16 + (lane & 15);   // this lane's v-row in the tile
    const int rx    = r & 7;                   // its read-swizzle key

    for (int t = t0; t < t0 + TPB; ++t) {
        // ---- convert staged regs -> swizzled LDS (8B ds_write_b64 granules)
        #pragma unroll
        for (int i = 0; i < 8; ++i) {
            const int row = (tid >> 5) + i * 8;
            uint2 val;
            val.x = ((unsigned)f2bf_rne(g[i].y) << 16) | f2bf_rne(g[i].x);
            val.y = ((unsigned)f2bf_rne(g[i].w) << 16) | f2bf_rne(g[i].z);
            *(uint2*)&eL[row * DD + ((s16 ^ (row & 7)) << 3) + (hw << 2)] = val;
        }

        // ---- issue next tile's loads NOW; they stream during compute
        if (t + 1 < t0 + TPB) {
            #pragma unroll
            for (int i = 0; i < 8; ++i)
                g[i] = ebase[(size_t)(t + 1) * F4T + tid + i * NTH];
        }

        // LDS writes visible to all waves; do NOT drain vmcnt (prefetch lives on)
        asm volatile("s_waitcnt lgkmcnt(0)" ::: "memory");
        __builtin_amdgcn_s_barrier();
        __builtin_amdgcn_sched_barrier(0);

        // ---- per-wave row norms (f32 over the bf16 tile). Lane covers row r,
        // quarter (lane>>4): 4 x ds_read_b128, then fold quarters via shfl.
        float pn = 0.f;
        #pragma unroll
        for (int j = 0; j < 4; ++j) {
            const int q = (lane >> 4) * 4 + j;
            const bf16x8 hh = *(const bf16x8*)&eL[r * DD + ((q ^ rx) << 3)];
            #pragma unroll
            for (int c = 0; c < 8; ++c) {
                const float x = bf2f((unsigned short)hh[c]);
                pn = fmaf(x, x, pn);
            }
        }
        pn += __shfl_xor(pn, 16);
        pn += __shfl_xor(pn, 32);   // all lanes: full ||row r||^2

        // ---- MFMA: B-col(v)=lane&15 (row r), k=(lane>>4)*8 + sl*32 + 0..7
        f32x4 acc = {0.f, 0.f, 0.f, 0.f};
        #pragma unroll
        for (int sl = 0; sl < 4; ++sl) {
            const int q = sl * 4 + (lane >> 4);
            const bf16x8 bfrag = *(const bf16x8*)&eL[r * DD + ((q ^ rx) << 3)];
            acc = __builtin_amdgcn_mfma_f32_16x16x32_bf16(afrag[sl], bfrag, acc, 0, 0, 0);
        }

        // ---- scaled store: D layout col(v)=lane&15, row(batch)=(lane>>4)*4+reg
        const float f = SCALE / fmaxf(sqrtf(pn), EPS);  // F.normalize semantics
        const int v = t * TVR + r;
        #pragma unroll
        for (int reg = 0; reg < 4; ++reg) {
            const int b = (lane >> 4) * 4 + reg;
            out[((size_t)b * SS + s) * VV + v] = acc[reg] * f;
        }

        // all waves done READING eL before next iteration overwrites it
        asm volatile("s_waitcnt lgkmcnt(0)" ::: "memory");
        __builtin_amdgcn_s_barrier();
        __builtin_amdgcn_sched_barrier(0);
    }
}

extern "C" void kernel_launch(void* const* d_in, const int* in_sizes, int n_in,
                              void* d_out, int out_size, void* d_ws, size_t ws_size,
                              hipStream_t stream) {
    const int*      tokens  = (const int*)d_in[0];
    const float*    scalars = (const float*)d_in[1];
    const float*    wvecs   = (const float*)d_in[2];
    const float*    emb     = (const float*)d_in[3];
    float*          out     = (float*)d_out;
    unsigned short* ctx_bf  = (unsigned short*)d_ws;   // S*B*D*2 = 196,608 bytes

    ctx_kernel<<<dim3(BB), dim3(64), 0, stream>>>(tokens, scalars, wvecs, ctx_bf);

    dim3 grid(BPS, SS);   // (25, 48) = 1200 blocks, 256 threads each
    logits_kernel<<<grid, dim3(NTH), 0, stream>>>(ctx_bf, emb, out);
}